// Round 13
// baseline (121.372 us; speedup 1.0000x reference)
//
#include <hip/hip_runtime.h>
#include <hip/hip_bf16.h>
#include <stdint.h>

#define B_ 16
#define S_ 2048
#define D_ 512
#define A_ 512
#define M_TOT (B_ * S_)

typedef __attribute__((ext_vector_type(4))) float f32x4;
typedef __attribute__((ext_vector_type(8))) short bf16x8;

__device__ inline unsigned short f2bf(float f) {
  union { float f; unsigned int u; } c; c.f = f;
  unsigned int u = c.u;
  unsigned int r = (u + 0x7fffu + ((u >> 16) & 1u)) >> 16;  // RNE
  return (unsigned short)r;
}

__device__ inline unsigned pk2bf(float x, float y) {
  __hip_bfloat162 p = __float22bfloat162_rn(float2{x, y});
  union { __hip_bfloat162 h; unsigned u; } c; c.h = p;
  return c.u;
}

__device__ inline float fast_tanh(float x) {
  float e = __expf(2.0f * x);
  return 1.0f - 2.0f * __builtin_amdgcn_rcpf(e + 1.0f);
}

__device__ inline void gload_lds16(const void* g, void* l) {
  __builtin_amdgcn_global_load_lds((const __attribute__((address_space(1))) void*)g,
                                   (__attribute__((address_space(3))) void*)l, 16, 0, 0);
}

// ---------------------------------------------------------------------------
// K0: pack [Wq;Wk] (each [512,512] f32, row=d, col=a) into WT bf16
// [A=512][Kcat=1024] (row=a, col=d-concat), i.e. B^T layout for the GEMM.
// ---------------------------------------------------------------------------
__global__ __launch_bounds__(256) void k0_pack_w(const float* __restrict__ Wq,
                                                 const float* __restrict__ Wk,
                                                 unsigned short* __restrict__ WT) {
  __shared__ unsigned short tile[64][65];
  int bid = blockIdx.x;
  int dt = bid & 15, at = bid >> 4;
  int d0 = dt * 64, a0 = at * 64;
  int t = threadIdx.x;
  int col = t & 63, rbase = t >> 6;
#pragma unroll
  for (int r8 = 0; r8 < 16; ++r8) {
    int row = r8 * 4 + rbase;
    int dcat = d0 + row;
    float f = (dcat < 512) ? Wq[(size_t)dcat * 512 + a0 + col]
                           : Wk[(size_t)(dcat - 512) * 512 + a0 + col];
    tile[row][col] = f2bf(f);
  }
  __syncthreads();
#pragma unroll
  for (int r8 = 0; r8 < 16; ++r8) {
    int arow = r8 * 4 + rbase;
    WT[(size_t)(a0 + arow) * 1024 + d0 + col] = tile[col][arow];
  }
}

// ---------------------------------------------------------------------------
// K1: scores partial. BM=256, BN=256 (cb half of A), BK=64 -> 16 phases
// (halved phase count: the ~2600cy/phase fixed overhead was ~50% of k1 at
// BK=32). 512 threads = 8 waves (2 wr x 4 wc), wave-tile 128x64 (8m x 4n,
// acc=128 regs). LDS 128 KiB dbuf. Per phase:
//   issueA(p+1)->regs (A FIRST: writeA's compiler-wait retires only A,
//   vmcnt(4), B rides through the MFMA burst) | stageB(p+1) | 64 MFMA/wave
//   | writeA(p+1) | vmcnt(0) lgkm(0) + barrier (safe drain; all ops have a
//   full ~2480cy phase of cover).
// Swizzle both sides: 128B rows, 8x16B chunks, chunk' = chunk ^ (row&7).
// XCD-paired decode: both cb of a strip share an XCD (A re-read = L2 hit).
// ---------------------------------------------------------------------------
__global__ __launch_bounds__(512, 1) void k1_scores(
    const float* __restrict__ Q, const float* __restrict__ K,
    const unsigned short* __restrict__ WT, const float* __restrict__ Wsv,
    float* __restrict__ partial) {
  __shared__ unsigned short Al[2][256 * 64];   // 2 x 32 KiB
  __shared__ unsigned short Bl[2][256 * 64];   // 2 x 32 KiB

  const int t = threadIdx.x;
  const int lane = t & 63, w = t >> 6;
  const int frow = lane & 15, fsl = lane >> 4;
  const int wr = w >> 2, wc = w & 3;

  const int bid = (int)blockIdx.x;
  const int wg = (bid & 7) * 32 + (bid >> 3);   // bijective (256 % 8 == 0)
  const int strip = wg >> 1, cb = wg & 1;
  const int row0 = strip * 256, col0 = cb * 256;

  // A staging: thread covers row ar (0..255), cols hc*32..+32 (8 float4).
  const int ar = t >> 1, hc = t & 1;

  float4 rA[8];

  auto issueA = [&](int kt) {
    const float* src = (kt < 8) ? Q : K;
    const float* ap = src + (size_t)(row0 + ar) * 512 + (kt & 7) * 64 + hc * 32;
#pragma unroll
    for (int i = 0; i < 8; ++i) rA[i] = *(const float4*)(ap + i * 4);
  };
  auto writeA = [&](int buf) {
    char* base = (char*)&Al[buf][0] + ar * 128;
#pragma unroll
    for (int i = 0; i < 4; ++i) {
      uint4 d;
      d.x = pk2bf(rA[2 * i].x, rA[2 * i].y);
      d.y = pk2bf(rA[2 * i].z, rA[2 * i].w);
      d.z = pk2bf(rA[2 * i + 1].x, rA[2 * i + 1].y);
      d.w = pk2bf(rA[2 * i + 1].z, rA[2 * i + 1].w);
      int chunk = hc * 4 + i;
      *(uint4*)(base + ((chunk ^ (ar & 7)) * 16)) = d;
    }
  };
  auto stageB = [&](int kt, int buf) {
#pragma unroll
    for (int q = 0; q < 4; ++q) {
      int p = (w * 4 + q) * 64 + lane;        // 16B-chunk index (0..2047)
      int row = p >> 3, c = p & 7;            // row = local output col
      const char* g = (const char*)WT + (size_t)(col0 + row) * 2048
                      + kt * 128 + ((c ^ (row & 7)) * 16);
      gload_lds16(g, (char*)&Bl[buf][0] + (size_t)(w * 4 + q) * 1024);
    }
  };

  f32x4 acc[8][4];
#pragma unroll
  for (int m = 0; m < 8; ++m)
#pragma unroll
    for (int n = 0; n < 4; ++n) acc[m][n] = (f32x4){0.f, 0.f, 0.f, 0.f};

  auto doMfma = [&](int CUR) {
    bf16x8 af[2][8], bfr[2][4];
#pragma unroll
    for (int ks = 0; ks < 2; ++ks) {
#pragma unroll
      for (int m = 0; m < 8; ++m) {
        int r = wr * 128 + m * 16 + frow;
        af[ks][m] = *(const bf16x8*)((const char*)&Al[CUR][0] + r * 128
                      + (((ks * 4 + fsl) ^ (r & 7)) * 16));
      }
#pragma unroll
      for (int n = 0; n < 4; ++n) {
        int r = wc * 64 + n * 16 + frow;
        bfr[ks][n] = *(const bf16x8*)((const char*)&Bl[CUR][0] + r * 128
                       + (((ks * 4 + fsl) ^ (r & 7)) * 16));
      }
    }
    __builtin_amdgcn_s_setprio(1);
#pragma unroll
    for (int ks = 0; ks < 2; ++ks)
#pragma unroll
      for (int m = 0; m < 8; ++m)
#pragma unroll
        for (int n = 0; n < 4; ++n)
          acc[m][n] = __builtin_amdgcn_mfma_f32_16x16x32_bf16(
              af[ks][m], bfr[ks][n], acc[m][n], 0, 0, 0);
    __builtin_amdgcn_s_setprio(0);
  };

  // ---- prologue: tile 0 staged ----
  issueA(0);
  stageB(0, 0);
  writeA(0);                       // compiler waits only the A(0) loads
  asm volatile("s_waitcnt vmcnt(0) lgkmcnt(0)" ::: "memory");
  __builtin_amdgcn_s_barrier();

  // ---- main loop: phases 0..14 ----
  for (int kt = 0; kt < 15; ++kt) {
    const int cur = kt & 1;
    issueA(kt + 1);                // A first (oldest in vmem queue)
    stageB(kt + 1, cur ^ 1);
    doMfma(cur);
    writeA(cur ^ 1);               // auto vmcnt(4): retires A, leaves B
    asm volatile("s_waitcnt vmcnt(0) lgkmcnt(0)" ::: "memory");
    __builtin_amdgcn_s_barrier();
  }
  // ---- tail: phase 15 (compute only) ----
  doMfma(1);

  // ---- epilogue: tanh * Ws, reduce over this block's 256 cols ----
  float wsv[4];
#pragma unroll
  for (int n = 0; n < 4; ++n) wsv[n] = Wsv[col0 + wc * 64 + n * 16 + frow];
  __syncthreads();                 // safe to alias Al for scw
  float* scw = (float*)&Al[0][0];  // [4][256]
#pragma unroll
  for (int m = 0; m < 8; ++m) {
#pragma unroll
    for (int ii = 0; ii < 4; ++ii) {
      float s = 0.f;
#pragma unroll
      for (int n = 0; n < 4; ++n)
        s += fast_tanh(acc[m][n][ii]) * wsv[n];
      s += __shfl_xor(s, 1);
      s += __shfl_xor(s, 2);
      s += __shfl_xor(s, 4);
      s += __shfl_xor(s, 8);
      if (frow == 0)
        scw[wc * 256 + wr * 128 + m * 16 + fsl * 4 + ii] = s;
    }
  }
  __syncthreads();
  if (t < 256) {
    float s = scw[t] + scw[256 + t] + scw[512 + t] + scw[768 + t];
    partial[(size_t)cb * M_TOT + row0 + t] = s;
  }
}

// ---------------------------------------------------------------------------
// K3 (fused softmax + V-weighted sum): block (dh, sc, b) re-derives the
// batch softmax from the two L2-hot partial rows, then computes
// upart[sc][b][dh-half]; dh==0 blocks write outw.
// ---------------------------------------------------------------------------
__global__ __launch_bounds__(256) void k3_vsum(const float* __restrict__ value,
                                               const float* __restrict__ partial,
                                               float* __restrict__ upart,
                                               float* __restrict__ outw) {
  int bid = blockIdx.x;
  int dh = bid & 1, sc = (bid >> 1) & 15, b = bid >> 5;
  int t = threadIdx.x;
  int lane = t & 63, wave = t >> 6;
  int dg = t & 63, sg = t >> 6;
  __shared__ float red[4], red2[4];
  __shared__ float wl[128];
  __shared__ f32x4 redv[4][64];

  float v[8];
  float mx = -1e30f;
#pragma unroll
  for (int e = 0; e < 8; ++e) {
    size_t o = (size_t)b * S_ + e * 256 + t;
    float p = partial[o] + partial[M_TOT + o];
    v[e] = p;
    mx = fmaxf(mx, p);
  }
  for (int off = 1; off < 64; off <<= 1) mx = fmaxf(mx, __shfl_xor(mx, off));
  if (lane == 0) red[wave] = mx;
  __syncthreads();
  mx = fmaxf(fmaxf(red[0], red[1]), fmaxf(red[2], red[3]));
  float sum = 0.f;
#pragma unroll
  for (int e = 0; e < 8; ++e) sum += expf(v[e] - mx);
  for (int off = 1; off < 64; off <<= 1) sum += __shfl_xor(sum, off);
  if (lane == 0) red2[wave] = sum;
  __syncthreads();
  sum = red2[0] + red2[1] + red2[2] + red2[3];
  float inv = 1.f / sum;

  int s0 = sc * 128;
  if (t < 128) {
    size_t o = (size_t)b * S_ + s0 + t;
    float ww = expf(partial[o] + partial[M_TOT + o] - mx) * inv;
    wl[t] = ww;
    if (dh == 0) outw[o] = ww;
  }
  __syncthreads();

  const float* vp = value + ((size_t)b * S_ + s0) * 512 + dh * 256 + dg * 4;
  f32x4 a = (f32x4){0.f, 0.f, 0.f, 0.f};
  for (int s = sg; s < 128; s += 4) {
    float4 v4 = *(const float4*)(vp + (size_t)s * 512);
    float ws = wl[s];
    a[0] += ws * v4.x; a[1] += ws * v4.y; a[2] += ws * v4.z; a[3] += ws * v4.w;
  }
  redv[sg][dg] = a;
  __syncthreads();
  if (sg == 0) {
    f32x4 r = redv[0][dg] + redv[1][dg] + redv[2][dg] + redv[3][dg];
    float* dst = upart + (size_t)(sc * 16 + b) * 512 + dh * 256 + dg * 4;
    dst[0] = r[0]; dst[1] = r[1]; dst[2] = r[2]; dst[3] = r[3];
  }
}

// ---------------------------------------------------------------------------
// K4: context[b,a] = sum_d u[b,d] * Wv[d,a]. fp32. 64 blocks.
// ---------------------------------------------------------------------------
__global__ __launch_bounds__(256) void k4_ctx(const float* __restrict__ upart,
                                              const float* __restrict__ Wv,
                                              float* __restrict__ out) {
  int b = blockIdx.x >> 2, q = blockIdx.x & 3;
  int t = threadIdx.x;
  int col = q * 128 + (t & 127), dhf = t >> 7;
  __shared__ float ul[512];
  __shared__ float part[2][128];
  for (int i = t; i < 512; i += 256) {
    float u = 0.f;
#pragma unroll
    for (int c = 0; c < 16; ++c) u += upart[(size_t)(c * 16 + b) * 512 + i];
    ul[i] = u;
  }
  __syncthreads();
  float acc = 0.f;
#pragma unroll 8
  for (int d = dhf * 256; d < dhf * 256 + 256; ++d)
    acc += ul[d] * Wv[(size_t)d * 512 + col];
  part[dhf][t & 127] = acc;
  __syncthreads();
  if (dhf == 0)
    out[(size_t)b * 512 + col] = part[0][t & 127] + part[1][t & 127];
}

// ---------------------------------------------------------------------------
extern "C" void kernel_launch(void* const* d_in, const int* in_sizes, int n_in,
                              void* d_out, int out_size, void* d_ws, size_t ws_size,
                              hipStream_t stream) {
  const float* Q  = (const float*)d_in[0];
  const float* Kk = (const float*)d_in[1];
  const float* V  = (const float*)d_in[2];
  const float* Wq = (const float*)d_in[3];
  const float* Wk = (const float*)d_in[4];
  const float* Wv = (const float*)d_in[5];
  const float* Ws = (const float*)d_in[6];
  float* out = (float*)d_out;

  char* ws = (char*)d_ws;
  unsigned short* WT = (unsigned short*)ws;                        // 1 MiB
  float* partial = (float*)(ws + (1 << 20));                       // 256 KiB: [2][32768]
  float* upart   = (float*)(ws + (1 << 20) + (512 << 10));         // 512 KiB

  float* outw = out + B_ * A_;   // attention weights region [B*S]

  k0_pack_w<<<dim3(128), dim3(256), 0, stream>>>(Wq, Wk, WT);
  k1_scores<<<dim3(256), dim3(512), 0, stream>>>(Q, Kk, WT, Ws, partial);
  k3_vsum<<<dim3(512), dim3(256), 0, stream>>>(V, partial, upart, outw);
  k4_ctx<<<dim3(64), dim3(256), 0, stream>>>(upart, Wv, out);
}

// Round 14
// 100.029 us; speedup vs baseline: 1.2134x; 1.2134x over previous
//
#include <hip/hip_runtime.h>
#include <hip/hip_bf16.h>
#include <stdint.h>

#define B_ 16
#define S_ 2048
#define D_ 512
#define A_ 512

typedef __attribute__((ext_vector_type(4))) float f32x4;
typedef __attribute__((ext_vector_type(8))) short bf16x8;

__device__ inline unsigned short f2bf(float f) {
  union { float f; unsigned int u; } c; c.f = f;
  unsigned int u = c.u;
  unsigned int r = (u + 0x7fffu + ((u >> 16) & 1u)) >> 16;  // RNE
  return (unsigned short)r;
}

__device__ inline unsigned pk2bf(float x, float y) {
  __hip_bfloat162 p = __float22bfloat162_rn(float2{x, y});
  union { __hip_bfloat162 h; unsigned u; } c; c.h = p;
  return c.u;
}

__device__ inline float fast_tanh(float x) {
  float e = __expf(2.0f * x);
  return 1.0f - 2.0f * __builtin_amdgcn_rcpf(e + 1.0f);
}

// ---------------------------------------------------------------------------
// K0: pack [Wq;Wk] (each [512,512] f32, row=d, col=a) into WT bf16
// [A=512][Kcat=1024] (row=a, col=d-concat), i.e. B^T layout for the GEMM.
// ---------------------------------------------------------------------------
__global__ __launch_bounds__(256) void k0_pack_w(const float* __restrict__ Wq,
                                                 const float* __restrict__ Wk,
                                                 unsigned short* __restrict__ WT) {
  __shared__ unsigned short tile[64][65];
  int bid = blockIdx.x;
  int dt = bid & 15, at = bid >> 4;
  int d0 = dt * 64, a0 = at * 64;
  int t = threadIdx.x;
  int col = t & 63, rbase = t >> 6;
#pragma unroll
  for (int r8 = 0; r8 < 16; ++r8) {
    int row = r8 * 4 + rbase;
    int dcat = d0 + row;
    float f = (dcat < 512) ? Wq[(size_t)dcat * 512 + a0 + col]
                           : Wk[(size_t)(dcat - 512) * 512 + a0 + col];
    tile[row][col] = f2bf(f);
  }
  __syncthreads();
#pragma unroll
  for (int r8 = 0; r8 < 16; ++r8) {
    int arow = r8 * 4 + rbase;
    WT[(size_t)(a0 + arow) * 1024 + d0 + col] = tile[col][arow];
  }
}

// ---------------------------------------------------------------------------
// K1: scores. r10 geometry (best measured, 66.5 us): BM=128, BN=512, BK=32,
// 32 phases, 512 threads = 8 waves, wave-tile 128x64 (8x4 frags, acc=128).
// SINGLE CHANGE vs r10: Bl LDS staging DELETED (Common-mistake #7 — WT is
// 1 MiB, fully L2-resident). B fragments load directly from global into
// registers: per lane one 16B read at WT[row*2048 + p*64 + fsl*16]
// (16 rows x 64B per instruction, L2-hot ~200cy, hidden under MFMA).
// Removes: B gload_lds + its vmcnt exposure + 64 KiB LDS + 64 of 96
// ds_read_b128 per CU-phase. A path unchanged (fp32 -> cvt_pk -> swizzled
// Al dbuf; issued 2 phases ahead; counted vmcnt(2) at the barrier).
// LDS swizzle (Al): 64B rows, 4x16B chunks, chunk' = chunk ^ ((row>>1)&3).
// ---------------------------------------------------------------------------
__global__ __launch_bounds__(512, 2) void k1_scores(
    const float* __restrict__ Q, const float* __restrict__ K,
    const unsigned short* __restrict__ WT, const float* __restrict__ Wsv,
    float* __restrict__ score) {
  __shared__ unsigned short Al[2][128 * 32];   // 2 x 8 KiB
  __shared__ float scw[8][128];                // 4 KiB

  const int t = threadIdx.x;
  const int lane = t & 63, w = t >> 6;
  const int frow = lane & 15, fsl = lane >> 4;
  const int row0 = (int)blockIdx.x * 128;

  // A staging: thread handles row ar, 8 floats at cols ak..ak+7 (one 16B chunk)
  const int ar = t >> 2, ak = (t & 3) * 8;
  const int abyte = ar * 64 + (((t & 3) ^ ((ar >> 1) & 3)) * 16);

  float4 rA0[2], rA1[2];

  auto issueA = [&](int p, float4* r) {
    const float* src = (p < 16) ? Q : K;
    const float* ap = src + (size_t)(row0 + ar) * 512 + ((p * 32) & 511) + ak;
    r[0] = *(const float4*)(ap);
    r[1] = *(const float4*)(ap + 4);
  };
  auto writeA = [&](const float4* r, int buf) {
    uint4 d;
    d.x = pk2bf(r[0].x, r[0].y);
    d.y = pk2bf(r[0].z, r[0].w);
    d.z = pk2bf(r[1].x, r[1].y);
    d.w = pk2bf(r[1].z, r[1].w);
    *(uint4*)((char*)&Al[buf][0] + abyte) = d;
  };

  // B fragment base for this lane: rows w*64 + n*16 + frow, slot fsl.
  const char* bbase = (const char*)WT + (size_t)(w * 64 + frow) * 2048 + fsl * 16;

  f32x4 acc[8][4];
#pragma unroll
  for (int m = 0; m < 8; ++m)
#pragma unroll
    for (int n = 0; n < 4; ++n) acc[m][n] = (f32x4){0.f, 0.f, 0.f, 0.f};

  const int ch = (fsl ^ ((frow >> 1) & 3)) * 16;

  auto doMfma = [&](int p, int CUR) {
    bf16x8 bfr[4];
#pragma unroll
    for (int n = 0; n < 4; ++n)
      bfr[n] = *(const bf16x8*)(bbase + (size_t)n * 16 * 2048 + p * 64);
    bf16x8 af[8];
#pragma unroll
    for (int m = 0; m < 8; ++m)
      af[m] = *(const bf16x8*)((const char*)&Al[CUR][0] + (m * 16 + frow) * 64 + ch);
    __builtin_amdgcn_s_setprio(1);
#pragma unroll
    for (int m = 0; m < 8; ++m)
#pragma unroll
      for (int n = 0; n < 4; ++n)
        acc[m][n] = __builtin_amdgcn_mfma_f32_16x16x32_bf16(af[m], bfr[n], acc[m][n], 0, 0, 0);
    __builtin_amdgcn_s_setprio(0);
  };

  // ---- prologue: A(0) staged; A(1) left in flight across the barrier ----
  issueA(0, rA0);
  __builtin_amdgcn_sched_barrier(0);
  issueA(1, rA1);
  writeA(rA0, 0);                       // compiler waits its own A(0) loads
  asm volatile("s_waitcnt vmcnt(2) lgkmcnt(0)" ::: "memory");
  __builtin_amdgcn_s_barrier();

  // ---- main loop: phases 0..29 ----
  auto phase = [&](int p, int CUR, float4* rCur, const float4* rNext) {
    issueA(p + 2, rCur);
    doMfma(p, CUR);
    writeA(rNext, CUR ^ 1);             // A(p+1), write-late
    asm volatile("s_waitcnt vmcnt(2) lgkmcnt(0)" ::: "memory");
    __builtin_amdgcn_s_barrier();
  };

  for (int kt2 = 0; kt2 < 15; ++kt2) {
    phase(2 * kt2 + 0, 0, rA0, rA1);
    phase(2 * kt2 + 1, 1, rA1, rA0);
  }

  // ---- peeled tail: phase 30 (no A issue), phase 31 (compute only) ----
  doMfma(30, 0);
  writeA(rA1, 1);                       // A(31)
  asm volatile("s_waitcnt vmcnt(0) lgkmcnt(0)" ::: "memory");
  __builtin_amdgcn_s_barrier();
  doMfma(31, 1);

  // ---- epilogue: tanh * Ws, reduce over all 512 cols ----
  float wsv[4];
#pragma unroll
  for (int n = 0; n < 4; ++n) wsv[n] = Wsv[w * 64 + n * 16 + frow];
#pragma unroll
  for (int m = 0; m < 8; ++m) {
#pragma unroll
    for (int ii = 0; ii < 4; ++ii) {
      float s = 0.f;
#pragma unroll
      for (int n = 0; n < 4; ++n)
        s += fast_tanh(acc[m][n][ii]) * wsv[n];
      s += __shfl_xor(s, 1);
      s += __shfl_xor(s, 2);
      s += __shfl_xor(s, 4);
      s += __shfl_xor(s, 8);
      if (frow == 0) scw[w][m * 16 + fsl * 4 + ii] = s;
    }
  }
  __syncthreads();
  if (t < 128) {
    float s = 0.f;
#pragma unroll
    for (int ww = 0; ww < 8; ++ww) s += scw[ww][t];
    score[row0 + t] = s;
  }
}

// ---------------------------------------------------------------------------
// K3 (fused softmax + V-weighted sum): block (dh, sc, b) re-derives the
// batch softmax from the L2-hot score row, then computes
// upart[sc][b][dh-half]; dh==0 blocks write outw.
// ---------------------------------------------------------------------------
__global__ __launch_bounds__(256) void k3_vsum(const float* __restrict__ value,
                                               const float* __restrict__ score,
                                               float* __restrict__ upart,
                                               float* __restrict__ outw) {
  int bid = blockIdx.x;
  int dh = bid & 1, sc = (bid >> 1) & 15, b = bid >> 5;
  int t = threadIdx.x;
  int lane = t & 63, wave = t >> 6;
  int dg = t & 63, sg = t >> 6;
  __shared__ float red[4], red2[4];
  __shared__ float wl[128];
  __shared__ f32x4 redv[4][64];

  float v[8];
  float mx = -1e30f;
#pragma unroll
  for (int e = 0; e < 8; ++e) {
    float p = score[(size_t)b * S_ + e * 256 + t];
    v[e] = p;
    mx = fmaxf(mx, p);
  }
  for (int off = 1; off < 64; off <<= 1) mx = fmaxf(mx, __shfl_xor(mx, off));
  if (lane == 0) red[wave] = mx;
  __syncthreads();
  mx = fmaxf(fmaxf(red[0], red[1]), fmaxf(red[2], red[3]));
  float sum = 0.f;
#pragma unroll
  for (int e = 0; e < 8; ++e) sum += expf(v[e] - mx);
  for (int off = 1; off < 64; off <<= 1) sum += __shfl_xor(sum, off);
  if (lane == 0) red2[wave] = sum;
  __syncthreads();
  sum = red2[0] + red2[1] + red2[2] + red2[3];
  float inv = 1.f / sum;

  int s0 = sc * 128;
  if (t < 128) {
    size_t o = (size_t)b * S_ + s0 + t;
    float ww = expf(score[o] - mx) * inv;
    wl[t] = ww;
    if (dh == 0) outw[o] = ww;
  }
  __syncthreads();

  const float* vp = value + ((size_t)b * S_ + s0) * 512 + dh * 256 + dg * 4;
  f32x4 a = (f32x4){0.f, 0.f, 0.f, 0.f};
  for (int s = sg; s < 128; s += 4) {
    float4 v4 = *(const float4*)(vp + (size_t)s * 512);
    float ws = wl[s];
    a[0] += ws * v4.x; a[1] += ws * v4.y; a[2] += ws * v4.z; a[3] += ws * v4.w;
  }
  redv[sg][dg] = a;
  __syncthreads();
  if (sg == 0) {
    f32x4 r = redv[0][dg] + redv[1][dg] + redv[2][dg] + redv[3][dg];
    float* dst = upart + (size_t)(sc * 16 + b) * 512 + dh * 256 + dg * 4;
    dst[0] = r[0]; dst[1] = r[1]; dst[2] = r[2]; dst[3] = r[3];
  }
}

// ---------------------------------------------------------------------------
// K4: context[b,a] = sum_d u[b,d] * Wv[d,a]. fp32. 64 blocks.
// ---------------------------------------------------------------------------
__global__ __launch_bounds__(256) void k4_ctx(const float* __restrict__ upart,
                                              const float* __restrict__ Wv,
                                              float* __restrict__ out) {
  int b = blockIdx.x >> 2, q = blockIdx.x & 3;
  int t = threadIdx.x;
  int col = q * 128 + (t & 127), dhf = t >> 7;
  __shared__ float ul[512];
  __shared__ float part[2][128];
  for (int i = t; i < 512; i += 256) {
    float u = 0.f;
#pragma unroll
    for (int c = 0; c < 16; ++c) u += upart[(size_t)(c * 16 + b) * 512 + i];
    ul[i] = u;
  }
  __syncthreads();
  float acc = 0.f;
#pragma unroll 8
  for (int d = dhf * 256; d < dhf * 256 + 256; ++d)
    acc += ul[d] * Wv[(size_t)d * 512 + col];
  part[dhf][t & 127] = acc;
  __syncthreads();
  if (dhf == 0)
    out[(size_t)b * 512 + col] = part[0][t & 127] + part[1][t & 127];
}

// ---------------------------------------------------------------------------
extern "C" void kernel_launch(void* const* d_in, const int* in_sizes, int n_in,
                              void* d_out, int out_size, void* d_ws, size_t ws_size,
                              hipStream_t stream) {
  const float* Q  = (const float*)d_in[0];
  const float* Kk = (const float*)d_in[1];
  const float* V  = (const float*)d_in[2];
  const float* Wq = (const float*)d_in[3];
  const float* Wk = (const float*)d_in[4];
  const float* Wv = (const float*)d_in[5];
  const float* Ws = (const float*)d_in[6];
  float* out = (float*)d_out;

  char* ws = (char*)d_ws;
  unsigned short* WT = (unsigned short*)ws;                        // 1 MiB
  float* score = (float*)(ws + (1 << 20));                         // 128 KiB
  float* upart = (float*)(ws + (1 << 20) + (512 << 10));           // 512 KiB

  float* outw = out + B_ * A_;   // attention weights region [B*S]

  k0_pack_w<<<dim3(128), dim3(256), 0, stream>>>(Wq, Wk, WT);
  k1_scores<<<dim3(256), dim3(512), 0, stream>>>(Q, Kk, WT, Ws, score);
  k3_vsum<<<dim3(512), dim3(256), 0, stream>>>(V, score, upart, outw);
  k4_ctx<<<dim3(64), dim3(256), 0, stream>>>(upart, Wv, out);
}

// Round 15
// 83.237 us; speedup vs baseline: 1.4582x; 1.2017x over previous
//
#include <hip/hip_runtime.h>
#include <hip/hip_bf16.h>
#include <stdint.h>

#define B_ 16
#define S_ 2048
#define D_ 512
#define A_ 512

typedef __attribute__((ext_vector_type(4))) float f32x4;
typedef __attribute__((ext_vector_type(8))) short bf16x8;

__device__ inline unsigned short f2bf(float f) {
  union { float f; unsigned int u; } c; c.f = f;
  unsigned int u = c.u;
  unsigned int r = (u + 0x7fffu + ((u >> 16) & 1u)) >> 16;  // RNE
  return (unsigned short)r;
}

__device__ inline unsigned pk2bf(float x, float y) {
  __hip_bfloat162 p = __float22bfloat162_rn(float2{x, y});
  union { __hip_bfloat162 h; unsigned u; } c; c.h = p;
  return c.u;
}

__device__ inline float fast_tanh(float x) {
  float e = __expf(2.0f * x);
  return 1.0f - 2.0f * __builtin_amdgcn_rcpf(e + 1.0f);
}

// ---------------------------------------------------------------------------
// K0: pack [Wq;Wk] (each [512,512] f32, row=d, col=a) into WT bf16
// [A=512][Kcat=1024] (row=a, col=d-concat), i.e. B^T layout for the GEMM.
// ---------------------------------------------------------------------------
__global__ __launch_bounds__(256) void k0_pack_w(const float* __restrict__ Wq,
                                                 const float* __restrict__ Wk,
                                                 unsigned short* __restrict__ WT) {
  __shared__ unsigned short tile[64][65];
  int bid = blockIdx.x;
  int dt = bid & 15, at = bid >> 4;
  int d0 = dt * 64, a0 = at * 64;
  int t = threadIdx.x;
  int col = t & 63, rbase = t >> 6;
#pragma unroll
  for (int r8 = 0; r8 < 16; ++r8) {
    int row = r8 * 4 + rbase;
    int dcat = d0 + row;
    float f = (dcat < 512) ? Wq[(size_t)dcat * 512 + a0 + col]
                           : Wk[(size_t)(dcat - 512) * 512 + a0 + col];
    tile[row][col] = f2bf(f);
  }
  __syncthreads();
#pragma unroll
  for (int r8 = 0; r8 < 16; ++r8) {
    int arow = r8 * 4 + rbase;
    WT[(size_t)(a0 + arow) * 1024 + d0 + col] = tile[col][arow];
  }
}

// ---------------------------------------------------------------------------
// K1: scores. r10 geometry: BM=128, BN=512, BK=32, 32 phases, 512 threads =
// 8 waves, wave-tile 128x64 (8x4 frags, acc=128).
// CHANGE vs r14 (which exposed B-L2 latency in-phase): B fragments are
// software-prefetched ONE PHASE AHEAD into named registers (b0/b1 alternate,
// static indexing). B loads issued at phase-p start for p+1 ride a full
// phase (~2000cy >> L2 ~200cy). With B never entering LDS, the barrier
// needs NO vmem drain: only lgkmcnt(0) (A ds_write) + raw s_barrier —
// in-flight A(p+2)/B(p+1) register loads cross the barrier untouched.
// A path unchanged from r10: issued 2 ahead, cvt_pk, swizzled 16 KiB dbuf.
// LDS swizzle (Al): 64B rows, 4x16B chunks, chunk' = chunk ^ ((row>>1)&3).
// ---------------------------------------------------------------------------
__global__ __launch_bounds__(512, 2) void k1_scores(
    const float* __restrict__ Q, const float* __restrict__ K,
    const unsigned short* __restrict__ WT, const float* __restrict__ Wsv,
    float* __restrict__ score) {
  __shared__ unsigned short Al[2][128 * 32];   // 2 x 8 KiB
  __shared__ float scw[8][128];                // 4 KiB

  const int t = threadIdx.x;
  const int lane = t & 63, w = t >> 6;
  const int frow = lane & 15, fsl = lane >> 4;
  const int row0 = (int)blockIdx.x * 128;

  // A staging: thread handles row ar, 8 floats at cols ak..ak+7 (one 16B chunk)
  const int ar = t >> 2, ak = (t & 3) * 8;
  const int abyte = ar * 64 + (((t & 3) ^ ((ar >> 1) & 3)) * 16);

  float4 rA0[2], rA1[2];
  bf16x8 b0[4], b1[4];

  auto issueA = [&](int p, float4* r) {
    const float* src = (p < 16) ? Q : K;
    const float* ap = src + (size_t)(row0 + ar) * 512 + ((p * 32) & 511) + ak;
    r[0] = *(const float4*)(ap);
    r[1] = *(const float4*)(ap + 4);
  };
  auto writeA = [&](const float4* r, int buf) {
    uint4 d;
    d.x = pk2bf(r[0].x, r[0].y);
    d.y = pk2bf(r[0].z, r[0].w);
    d.z = pk2bf(r[1].x, r[1].y);
    d.w = pk2bf(r[1].z, r[1].w);
    *(uint4*)((char*)&Al[buf][0] + abyte) = d;
  };

  // B fragment base for this lane: rows w*64 + n*16 + frow, slot fsl.
  const char* bbase = (const char*)WT + (size_t)(w * 64 + frow) * 2048 + fsl * 16;
  auto prefB = [&](int p, bf16x8* bb) {
#pragma unroll
    for (int n = 0; n < 4; ++n)
      bb[n] = *(const bf16x8*)(bbase + (size_t)n * 16 * 2048 + p * 64);
  };

  f32x4 acc[8][4];
#pragma unroll
  for (int m = 0; m < 8; ++m)
#pragma unroll
    for (int n = 0; n < 4; ++n) acc[m][n] = (f32x4){0.f, 0.f, 0.f, 0.f};

  const int ch = (fsl ^ ((frow >> 1) & 3)) * 16;

  auto doMfma = [&](int CUR, const bf16x8* bb) {
    bf16x8 af[8];
#pragma unroll
    for (int m = 0; m < 8; ++m)
      af[m] = *(const bf16x8*)((const char*)&Al[CUR][0] + (m * 16 + frow) * 64 + ch);
    __builtin_amdgcn_s_setprio(1);
#pragma unroll
    for (int m = 0; m < 8; ++m)
#pragma unroll
      for (int n = 0; n < 4; ++n)
        acc[m][n] = __builtin_amdgcn_mfma_f32_16x16x32_bf16(af[m], bb[n], acc[m][n], 0, 0, 0);
    __builtin_amdgcn_s_setprio(0);
  };

  // ---- prologue: A(0) staged, B(0) prefetched; A(1) issued ----
  issueA(0, rA0);
  prefB(0, b0);
  writeA(rA0, 0);                       // compiler waits its own A(0) loads
  issueA(1, rA1);
  asm volatile("s_waitcnt lgkmcnt(0)" ::: "memory");
  __builtin_amdgcn_s_barrier();

  // ---- main loop: phases 0..29 ----
  auto phase = [&](int p, int CUR, bf16x8* bcur, bf16x8* bnxt,
                   float4* rCur, const float4* rNext) {
    prefB(p + 1, bnxt);                 // rides the whole phase
    issueA(p + 2, rCur);
    doMfma(CUR, bcur);
    writeA(rNext, CUR ^ 1);             // A(p+1), write-late
    asm volatile("s_waitcnt lgkmcnt(0)" ::: "memory");
    __builtin_amdgcn_s_barrier();
  };

  for (int kt2 = 0; kt2 < 15; ++kt2) {
    phase(2 * kt2 + 0, 0, b0, b1, rA0, rA1);
    phase(2 * kt2 + 1, 1, b1, b0, rA1, rA0);
  }

  // ---- peeled tail: phase 30 (no A issue), phase 31 (compute only) ----
  prefB(31, b1);
  doMfma(0, b0);
  writeA(rA1, 1);                       // A(31)
  asm volatile("s_waitcnt lgkmcnt(0)" ::: "memory");
  __builtin_amdgcn_s_barrier();
  doMfma(1, b1);

  // ---- epilogue: tanh * Ws, reduce over all 512 cols ----
  float wsv[4];
#pragma unroll
  for (int n = 0; n < 4; ++n) wsv[n] = Wsv[w * 64 + n * 16 + frow];
#pragma unroll
  for (int m = 0; m < 8; ++m) {
#pragma unroll
    for (int ii = 0; ii < 4; ++ii) {
      float s = 0.f;
#pragma unroll
      for (int n = 0; n < 4; ++n)
        s += fast_tanh(acc[m][n][ii]) * wsv[n];
      s += __shfl_xor(s, 1);
      s += __shfl_xor(s, 2);
      s += __shfl_xor(s, 4);
      s += __shfl_xor(s, 8);
      if (frow == 0) scw[w][m * 16 + fsl * 4 + ii] = s;
    }
  }
  __syncthreads();
  if (t < 128) {
    float s = 0.f;
#pragma unroll
    for (int ww = 0; ww < 8; ++ww) s += scw[ww][t];
    score[row0 + t] = s;
  }
}

// ---------------------------------------------------------------------------
// K3 (fused softmax + V-weighted sum): block (dh, sc, b) re-derives the
// batch softmax from the L2-hot score row, then computes
// upart[sc][b][dh-half]; dh==0 blocks write outw.
// ---------------------------------------------------------------------------
__global__ __launch_bounds__(256) void k3_vsum(const float* __restrict__ value,
                                               const float* __restrict__ score,
                                               float* __restrict__ upart,
                                               float* __restrict__ outw) {
  int bid = blockIdx.x;
  int dh = bid & 1, sc = (bid >> 1) & 15, b = bid >> 5;
  int t = threadIdx.x;
  int lane = t & 63, wave = t >> 6;
  int dg = t & 63, sg = t >> 6;
  __shared__ float red[4], red2[4];
  __shared__ float wl[128];
  __shared__ f32x4 redv[4][64];

  float v[8];
  float mx = -1e30f;
#pragma unroll
  for (int e = 0; e < 8; ++e) {
    float p = score[(size_t)b * S_ + e * 256 + t];
    v[e] = p;
    mx = fmaxf(mx, p);
  }
  for (int off = 1; off < 64; off <<= 1) mx = fmaxf(mx, __shfl_xor(mx, off));
  if (lane == 0) red[wave] = mx;
  __syncthreads();
  mx = fmaxf(fmaxf(red[0], red[1]), fmaxf(red[2], red[3]));
  float sum = 0.f;
#pragma unroll
  for (int e = 0; e < 8; ++e) sum += expf(v[e] - mx);
  for (int off = 1; off < 64; off <<= 1) sum += __shfl_xor(sum, off);
  if (lane == 0) red2[wave] = sum;
  __syncthreads();
  sum = red2[0] + red2[1] + red2[2] + red2[3];
  float inv = 1.f / sum;

  int s0 = sc * 128;
  if (t < 128) {
    size_t o = (size_t)b * S_ + s0 + t;
    float ww = expf(score[o] - mx) * inv;
    wl[t] = ww;
    if (dh == 0) outw[o] = ww;
  }
  __syncthreads();

  const float* vp = value + ((size_t)b * S_ + s0) * 512 + dh * 256 + dg * 4;
  f32x4 a = (f32x4){0.f, 0.f, 0.f, 0.f};
  for (int s = sg; s < 128; s += 4) {
    float4 v4 = *(const float4*)(vp + (size_t)s * 512);
    float ws = wl[s];
    a[0] += ws * v4.x; a[1] += ws * v4.y; a[2] += ws * v4.z; a[3] += ws * v4.w;
  }
  redv[sg][dg] = a;
  __syncthreads();
  if (sg == 0) {
    f32x4 r = redv[0][dg] + redv[1][dg] + redv[2][dg] + redv[3][dg];
    float* dst = upart + (size_t)(sc * 16 + b) * 512 + dh * 256 + dg * 4;
    dst[0] = r[0]; dst[1] = r[1]; dst[2] = r[2]; dst[3] = r[3];
  }
}

// ---------------------------------------------------------------------------
// K4: context[b,a] = sum_d u[b,d] * Wv[d,a]. fp32. 64 blocks.
// ---------------------------------------------------------------------------
__global__ __launch_bounds__(256) void k4_ctx(const float* __restrict__ upart,
                                              const float* __restrict__ Wv,
                                              float* __restrict__ out) {
  int b = blockIdx.x >> 2, q = blockIdx.x & 3;
  int t = threadIdx.x;
  int col = q * 128 + (t & 127), dhf = t >> 7;
  __shared__ float ul[512];
  __shared__ float part[2][128];
  for (int i = t; i < 512; i += 256) {
    float u = 0.f;
#pragma unroll
    for (int c = 0; c < 16; ++c) u += upart[(size_t)(c * 16 + b) * 512 + i];
    ul[i] = u;
  }
  __syncthreads();
  float acc = 0.f;
#pragma unroll 8
  for (int d = dhf * 256; d < dhf * 256 + 256; ++d)
    acc += ul[d] * Wv[(size_t)d * 512 + col];
  part[dhf][t & 127] = acc;
  __syncthreads();
  if (dhf == 0)
    out[(size_t)b * 512 + col] = part[0][t & 127] + part[1][t & 127];
}

// ---------------------------------------------------------------------------
extern "C" void kernel_launch(void* const* d_in, const int* in_sizes, int n_in,
                              void* d_out, int out_size, void* d_ws, size_t ws_size,
                              hipStream_t stream) {
  const float* Q  = (const float*)d_in[0];
  const float* Kk = (const float*)d_in[1];
  const float* V  = (const float*)d_in[2];
  const float* Wq = (const float*)d_in[3];
  const float* Wk = (const float*)d_in[4];
  const float* Wv = (const float*)d_in[5];
  const float* Ws = (const float*)d_in[6];
  float* out = (float*)d_out;

  char* ws = (char*)d_ws;
  unsigned short* WT = (unsigned short*)ws;                        // 1 MiB
  float* score = (float*)(ws + (1 << 20));                         // 128 KiB
  float* upart = (float*)(ws + (1 << 20) + (512 << 10));           // 512 KiB

  float* outw = out + B_ * A_;   // attention weights region [B*S]

  k0_pack_w<<<dim3(128), dim3(256), 0, stream>>>(Wq, Wk, WT);
  k1_scores<<<dim3(256), dim3(512), 0, stream>>>(Q, Kk, WT, Ws, score);
  k3_vsum<<<dim3(512), dim3(256), 0, stream>>>(V, score, upart, outw);
  k4_ctx<<<dim3(64), dim3(256), 0, stream>>>(upart, Wv, out);
}